// Round 3
// baseline (411.183 us; speedup 1.0000x reference)
//
#include <hip/hip_runtime.h>

typedef __attribute__((ext_vector_type(8))) short bf16x8;
typedef __attribute__((ext_vector_type(4))) float f32x4;
typedef unsigned short u16;
typedef unsigned int u32;
typedef __attribute__((address_space(1))) const u32 gu32;
typedef __attribute__((address_space(3))) u32 lu32;

__device__ __forceinline__ float bf2f(u16 u) {
  union { u32 i; float f; } c; c.i = ((u32)u) << 16; return c.f;
}
__device__ __forceinline__ u16 f2bf(float f) {
  union { float f; u32 i; } c; c.f = f;
  u32 u = c.i;
  u32 r = (u + 0x7FFFu + ((u >> 16) & 1u)) >> 16;  // RNE
  return (u16)r;
}

// async 16B global->LDS (linear dest: wave-uniform base + lane*16)
__device__ __forceinline__ void gld16(const void* g, void* l) {
  __builtin_amdgcn_global_load_lds((gu32*)g, (lu32*)l, 16, 0, 0);
}

// ---------------- CSR / normalization build ----------------

__global__ void k_init_deg(int* deg, int n) {
  int i = blockIdx.x * 256 + threadIdx.x;
  if (i < n) deg[i] = 1;  // self-loop
}

__global__ void k_count(const int* __restrict__ ei, int* deg, int E) {
  int e = blockIdx.x * 256 + threadIdx.x;
  if (e < E) atomicAdd(&deg[ei[E + e]], 1);  // dst = edge_index[1][e]
}

__global__ void k_blocksum(const int* __restrict__ deg, int* bsum, int n) {
  __shared__ int s[256];
  int t = threadIdx.x;
  int i = blockIdx.x * 256 + t;
  s[t] = (i < n) ? (deg[i] - 1) : 0;
  __syncthreads();
  for (int o = 128; o > 0; o >>= 1) {
    if (t < o) s[t] += s[t + o];
    __syncthreads();
  }
  if (t == 0) bsum[blockIdx.x] = s[0];
}

__global__ void k_scanb(const int* __restrict__ bsum, int* bofs, int nb) {
  __shared__ int s[256];
  int t = threadIdx.x;
  int v = (t < nb) ? bsum[t] : 0;
  s[t] = v;
  __syncthreads();
  for (int o = 1; o < 256; o <<= 1) {
    int x = (t >= o) ? s[t - o] : 0;
    __syncthreads();
    s[t] += x;
    __syncthreads();
  }
  bofs[t] = s[t] - v;  // exclusive
}

__global__ void k_rowptr(const int* __restrict__ deg, const int* __restrict__ bofs,
                         int* rowptr, int* cursor, float* dinv, int n) {
  __shared__ int s[256];
  int t = threadIdx.x;
  int i = blockIdx.x * 256 + t;
  int d = (i < n) ? deg[i] : 1;
  int v = (i < n) ? (d - 1) : 0;
  s[t] = v;
  __syncthreads();
  for (int o = 1; o < 256; o <<= 1) {
    int x = (t >= o) ? s[t - o] : 0;
    __syncthreads();
    s[t] += x;
    __syncthreads();
  }
  int excl = s[t] - v + bofs[blockIdx.x];
  if (i < n) {
    rowptr[i] = excl;
    cursor[i] = excl;
    dinv[i] = rsqrtf((float)d);
    if (i == n - 1) rowptr[n] = excl + v;
  }
}

// pack (src, dinv[src]) per edge
__global__ void k_fill(const int* __restrict__ ei, int* cursor,
                       const float* __restrict__ dinv, int2* colw, int E) {
  int e = blockIdx.x * 256 + threadIdx.x;
  if (e >= E) return;
  int s = ei[e];
  int d = ei[E + e];
  int pos = atomicAdd(&cursor[d], 1);
  colw[pos] = make_int2(s, __float_as_int(dinv[s]));
}

// transpose + bf16 convert weights: W[K][N] f32 -> Wt[N][K] bf16
__global__ void k_twt(const float* __restrict__ W, u16* __restrict__ Wt, int K, int N) {
  int i = blockIdx.x * 256 + threadIdx.x;
  if (i >= K * N) return;
  int k = i / N, n = i - k * N;
  Wt[n * K + k] = f2bf(W[i]);
}

// ---------------- GEMM: C[M,ldc](bf16) = A[M,K] @ Bt[*,K]^T ----------------
// BM x 128 tile, BK=32, 4 waves (2x2 of (BM/2)x64), bf16 LDS both operands.
// A fp32 path: reg-staged (load early / cvt_pk+ds_write late, T14 split).
// A bf16 path + B: global_load_lds with pre-swizzled source, swizzled ds_read.

template <bool AF32, int K, int BM>
__launch_bounds__(256, 4)
__global__ void gemm_kernel(const void* __restrict__ Ap, const u16* __restrict__ Bt,
                            u16* __restrict__ C, int M, int ldc) {
  constexpr int NT = K / 32;
  constexpr int AE = BM * 32;          // A elems (bf16) per buffer
  constexpr int WROWS = BM / 2;        // wave tile rows
  constexpr int FI = WROWS / 16;       // A fragments per wave
  constexpr int NJA = BM / 64;         // A gld16 issues (bf16 path)
  __shared__ u16 As_[2][AE];
  __shared__ u16 Bs_[2][4096];

  const int tid = threadIdx.x;
  const int lane = tid & 63;
  const int wid = tid >> 6;
  const int wr = wid >> 1, wc = wid & 1;
  const long brow = (long)blockIdx.x * BM;
  const long bcol = (long)blockIdx.y * 128;

  // B staging ptrs (pre-swizzled global, linear LDS dest)
  const u16* bgp[2];
  u16* blp[2];
#pragma unroll
  for (int j = 0; j < 2; ++j) {
    int idx = j * 256 + tid;
    int row = idx >> 2;
    int u = (idx & 3) ^ (row & 3);
    bgp[j] = Bt + (bcol + row) * (long)K + u * 8;
    blp[j] = &Bs_[0][idx * 8];
  }

  // A staging state
  const float* apf = nullptr;
  int arow = 0, au0 = 0, au1 = 0;
  const u16* agp[NJA];
  u16* alp[NJA];
  if constexpr (AF32) {
    arow = tid >> 1;               // BM=128: row staged by this thread
    int khalf = tid & 1;           // which 16-float half of the 32-k row
    long grow = brow + arow; if (grow > (long)M - 1) grow = M - 1;
    apf = (const float*)Ap + grow * (long)K + khalf * 16;
    int sw = arow & 3;
    au0 = (2 * khalf) ^ sw;
    au1 = (2 * khalf + 1) ^ sw;
  } else {
#pragma unroll
    for (int j = 0; j < NJA; ++j) {
      int idx = j * 256 + tid;
      int row = idx >> 2;
      int u = (idx & 3) ^ (row & 3);
      long grow = brow + row; if (grow > (long)M - 1) grow = M - 1;
      agp[j] = (const u16*)Ap + grow * (long)K + u * 8;
      alp[j] = &As_[0][idx * 8];
    }
  }

  float4 fa[4];
  auto loadA = [&](int kt) {  // AF32 only: issue 4x float4 loads (early)
    const float4* p = (const float4*)(apf + kt * 32);
#pragma unroll
    for (int i = 0; i < 4; ++i) fa[i] = p[i];
  };
  auto writeA = [&](int buf) {  // AF32 only: cvt + swizzled ds_write (late)
    union { u32 w[8]; uint4 v[2]; } pk;
    asm("v_cvt_pk_bf16_f32 %0, %1, %2" : "=v"(pk.w[0]) : "v"(fa[0].x), "v"(fa[0].y));
    asm("v_cvt_pk_bf16_f32 %0, %1, %2" : "=v"(pk.w[1]) : "v"(fa[0].z), "v"(fa[0].w));
    asm("v_cvt_pk_bf16_f32 %0, %1, %2" : "=v"(pk.w[2]) : "v"(fa[1].x), "v"(fa[1].y));
    asm("v_cvt_pk_bf16_f32 %0, %1, %2" : "=v"(pk.w[3]) : "v"(fa[1].z), "v"(fa[1].w));
    asm("v_cvt_pk_bf16_f32 %0, %1, %2" : "=v"(pk.w[4]) : "v"(fa[2].x), "v"(fa[2].y));
    asm("v_cvt_pk_bf16_f32 %0, %1, %2" : "=v"(pk.w[5]) : "v"(fa[2].z), "v"(fa[2].w));
    asm("v_cvt_pk_bf16_f32 %0, %1, %2" : "=v"(pk.w[6]) : "v"(fa[3].x), "v"(fa[3].y));
    asm("v_cvt_pk_bf16_f32 %0, %1, %2" : "=v"(pk.w[7]) : "v"(fa[3].z), "v"(fa[3].w));
    *(uint4*)&As_[buf][arow * 32 + au0 * 8] = pk.v[0];
    *(uint4*)&As_[buf][arow * 32 + au1 * 8] = pk.v[1];
  };
  auto stageB = [&](int kt, int buf) {
#pragma unroll
    for (int j = 0; j < 2; ++j) gld16(bgp[j] + kt * 32, blp[j] + buf * 4096);
  };
  auto stageAg = [&](int kt, int buf) {
#pragma unroll
    for (int j = 0; j < NJA; ++j) gld16(agp[j] + kt * 32, alp[j] + buf * AE);
  };

  f32x4 acc[FI][4];
#pragma unroll
  for (int i = 0; i < FI; i++)
#pragma unroll
    for (int j = 0; j < 4; j++) acc[i][j] = (f32x4){0.f, 0.f, 0.f, 0.f};

  // prologue: tile 0 into buf 0
  if constexpr (AF32) {
    loadA(0);
    stageB(0, 0);
    writeA(0);
  } else {
    stageAg(0, 0);
    stageB(0, 0);
  }
  __syncthreads();

  int cur = 0;
  for (int kt = 0; kt < NT; ++kt) {
    const bool more = (kt + 1 < NT);
    if constexpr (AF32) {
      if (more) { loadA(kt + 1); stageB(kt + 1, cur ^ 1); }
    } else {
      if (more) { stageAg(kt + 1, cur ^ 1); stageB(kt + 1, cur ^ 1); }
    }

    bf16x8 af[FI], bfq[4];
#pragma unroll
    for (int i = 0; i < FI; i++) {
      const int row = wr * WROWS + i * 16 + (lane & 15);
      const int u = (lane >> 4) ^ (row & 3);
      af[i] = *(const bf16x8*)&As_[cur][row * 32 + u * 8];
    }
#pragma unroll
    for (int j = 0; j < 4; j++) {
      const int row = wc * 64 + j * 16 + (lane & 15);
      const int u = (lane >> 4) ^ (row & 3);
      bfq[j] = *(const bf16x8*)&Bs_[cur][row * 32 + u * 8];
    }
#pragma unroll
    for (int i = 0; i < FI; i++)
#pragma unroll
      for (int j = 0; j < 4; j++)
        acc[i][j] = __builtin_amdgcn_mfma_f32_16x16x32_bf16(af[i], bfq[j], acc[i][j], 0, 0, 0);

    if constexpr (AF32) {
      if (more) writeA(cur ^ 1);  // vmcnt-wait on fa hidden behind the MFMAs above
    }
    __syncthreads();
    cur ^= 1;
  }

#pragma unroll
  for (int i = 0; i < FI; i++) {
    const long r0 = brow + wr * WROWS + i * 16 + ((lane >> 4) * 4);
#pragma unroll
    for (int j = 0; j < 4; j++) {
      const long cc = bcol + wc * 64 + j * 16 + (lane & 15);
#pragma unroll
      for (int q = 0; q < 4; q++) {
        long r = r0 + q;
        if (r < M) C[r * (long)ldc + cc] = f2bf(acc[i][j][q]);
      }
    }
  }
}

// ---------------- Channel-sliced aggregation (XCD-pinned slices) ----------------
// pass p = blockIdx.x & (NP-1): each XCD's L2 caches only a 50K x 32ch (3.2MB)
// slice of hin -> gathers served from XCD-local L2 instead of L3 fabric.
// Wave: 8 edge-slots x 8 lanes x 4 ch; slot-reduce via 3 shfl_xor.

__device__ __forceinline__ float sigmoidf_(float x) { return 1.f / (1.f + __expf(-x)); }

template <int ROWCH, int NP, bool RELU>
__launch_bounds__(256)
__global__ void agg_kernel(const u16* __restrict__ hin, const int* __restrict__ rowptr,
                           const int2* __restrict__ colw, const float* __restrict__ dinv,
                           const float* __restrict__ bias, void* __restrict__ outv, int n) {
  const int lane = threadIdx.x & 63;
  const int wid = threadIdx.x >> 6;
  const int p = blockIdx.x & (NP - 1);
  const int chunk = blockIdx.x / NP;
  const int slot = lane >> 3, li = lane & 7;
  const int choff = (p << 5) + (li << 2);  // u16 offset of this lane's 4 channels

  for (int i = 0; i < 8; ++i) {
    const int node = chunk * 32 + wid * 8 + i;
    if (node >= n) break;  // wave-uniform
    const float di = dinv[node];
    const int r0 = rowptr[node], r1 = rowptr[node + 1];
    float a0 = 0.f, a1 = 0.f, a2 = 0.f, a3 = 0.f;
    for (int e0 = r0; e0 < r1; e0 += 8) {
      int ee = e0 + slot;
      int ec = ee < r1 ? ee : r1 - 1;
      int2 c = colw[ec];
      float w = ee < r1 ? __int_as_float(c.y) : 0.f;
      const ushort4 v = *(const ushort4*)(hin + (size_t)c.x * ROWCH + choff);
      a0 += w * bf2f(v.x); a1 += w * bf2f(v.y);
      a2 += w * bf2f(v.z); a3 += w * bf2f(v.w);
    }
    a0 += __shfl_xor(a0, 8);  a1 += __shfl_xor(a1, 8);
    a2 += __shfl_xor(a2, 8);  a3 += __shfl_xor(a3, 8);
    a0 += __shfl_xor(a0, 16); a1 += __shfl_xor(a1, 16);
    a2 += __shfl_xor(a2, 16); a3 += __shfl_xor(a3, 16);
    a0 += __shfl_xor(a0, 32); a1 += __shfl_xor(a1, 32);
    a2 += __shfl_xor(a2, 32); a3 += __shfl_xor(a3, 32);
    if (lane < 8) {
      const int co = (p << 5) + (lane << 2);
      const ushort4 sv = *(const ushort4*)(hin + (size_t)node * ROWCH + co);
      const float dd = di * di;
      const float4 bb = *(const float4*)(bias + co);
      float y0 = di * a0 + dd * bf2f(sv.x) + bb.x;
      float y1 = di * a1 + dd * bf2f(sv.y) + bb.y;
      float y2 = di * a2 + dd * bf2f(sv.z) + bb.z;
      float y3 = di * a3 + dd * bf2f(sv.w) + bb.w;
      if constexpr (RELU) {
        y0 = fmaxf(y0, 0.f); y1 = fmaxf(y1, 0.f);
        y2 = fmaxf(y2, 0.f); y3 = fmaxf(y3, 0.f);
        ushort4 ov;
        ov.x = f2bf(y0); ov.y = f2bf(y1); ov.z = f2bf(y2); ov.w = f2bf(y3);
        *(ushort4*)((u16*)outv + (size_t)node * ROWCH + co) = ov;
      } else {
        *(float4*)((float*)outv + (size_t)node * ROWCH + co) =
            make_float4(sigmoidf_(y0), sigmoidf_(y1), sigmoidf_(y2), sigmoidf_(y3));
      }
    }
  }
}

// ---------------- launch ----------------

extern "C" void kernel_launch(void* const* d_in, const int* in_sizes, int n_in,
                              void* d_out, int out_size, void* d_ws, size_t ws_size,
                              hipStream_t stream) {
  const float* x  = (const float*)d_in[0];
  const float* W1 = (const float*)d_in[1];
  const float* b1 = (const float*)d_in[2];
  const float* W2 = (const float*)d_in[3];
  const float* b2 = (const float*)d_in[4];
  const int*   ei = (const int*)d_in[5];

  const int N = in_sizes[0] / 512;
  const int E = in_sizes[5] / 2;
  const int Mpad = (N + 127) & ~127;
  float* outp = (float*)d_out;

  char* w = (char*)d_ws;
  size_t off = 0;
  auto take = [&](size_t bytes) -> void* {
    void* p = w + off;
    off = (off + bytes + 255) & ~(size_t)255;
    return p;
  };
  u16*   h0     = (u16*)take((size_t)Mpad * 256 * 2);
  u16*   hb     = (u16*)take((size_t)Mpad * 256 * 2);
  u16*   h2     = (u16*)take((size_t)Mpad * 128 * 2);
  u16*   W1t    = (u16*)take(256 * 512 * 2);
  u16*   W2t    = (u16*)take(128 * 256 * 2);
  int*   deg    = (int*)take((size_t)N * 4);
  float* dinv   = (float*)take((size_t)N * 4);
  int*   rowptr = (int*)take((size_t)(N + 1) * 4);
  int*   cursor = (int*)take((size_t)N * 4);
  int2*  colw   = (int2*)take((size_t)E * 8);
  int*   bsum   = (int*)take(256 * 4);
  int*   bofs   = (int*)take(256 * 4);
  (void)ws_size; (void)n_in; (void)out_size;

  const int nb = (N + 255) / 256;  // <=256 required by k_scanb
  const int eb = (E + 255) / 256;

  k_init_deg<<<nb, 256, 0, stream>>>(deg, N);
  k_count<<<eb, 256, 0, stream>>>(ei, deg, E);
  k_blocksum<<<nb, 256, 0, stream>>>(deg, bsum, N);
  k_scanb<<<1, 256, 0, stream>>>(bsum, bofs, nb);
  k_rowptr<<<nb, 256, 0, stream>>>(deg, bofs, rowptr, cursor, dinv, N);
  k_fill<<<eb, 256, 0, stream>>>(ei, cursor, dinv, colw, E);
  k_twt<<<(512 * 256 + 255) / 256, 256, 0, stream>>>(W1, W1t, 512, 256);
  k_twt<<<(256 * 128 + 255) / 256, 256, 0, stream>>>(W2, W2t, 256, 128);

  const int chunks = (N + 31) / 32;

  dim3 g1(Mpad / 128, 2);
  gemm_kernel<true, 512, 128><<<g1, 256, 0, stream>>>((const void*)x, W1t, h0, N, 256);
  agg_kernel<256, 8, true><<<chunks * 8, 256, 0, stream>>>(h0, rowptr, colw, dinv, b1, hb, N);
  dim3 g2(Mpad / 64, 1);
  gemm_kernel<false, 256, 64><<<g2, 256, 0, stream>>>((const void*)hb, W2t, h2, Mpad, 128);
  agg_kernel<128, 4, false><<<chunks * 4, 256, 0, stream>>>(h2, rowptr, colw, dinv, b2, outp, N);
}

// Round 4
// 252.064 us; speedup vs baseline: 1.6313x; 1.6313x over previous
//
#include <hip/hip_runtime.h>

typedef __attribute__((ext_vector_type(8))) short bf16x8;
typedef __attribute__((ext_vector_type(4))) float f32x4;
typedef unsigned short u16;
typedef unsigned int u32;
typedef __attribute__((address_space(1))) const u32 gu32;
typedef __attribute__((address_space(3))) u32 lu32;

__device__ __forceinline__ float bf2f(u16 u) {
  union { u32 i; float f; } c; c.i = ((u32)u) << 16; return c.f;
}
__device__ __forceinline__ u16 f2bf(float f) {
  union { float f; u32 i; } c; c.f = f;
  u32 u = c.i;
  u32 r = (u + 0x7FFFu + ((u >> 16) & 1u)) >> 16;  // RNE
  return (u16)r;
}

// async 16B global->LDS (linear dest: wave-uniform base + lane*16)
__device__ __forceinline__ void gld16(const void* g, void* l) {
  __builtin_amdgcn_global_load_lds((gu32*)g, (lu32*)l, 16, 0, 0);
}

// ---------------- CSR / normalization build ----------------

__global__ void k_init_deg(int* deg, int n) {
  int i = blockIdx.x * 256 + threadIdx.x;
  if (i < n) deg[i] = 1;  // self-loop
}

__global__ void k_count(const int* __restrict__ ei, int* deg, int E) {
  int e = blockIdx.x * 256 + threadIdx.x;
  if (e < E) atomicAdd(&deg[ei[E + e]], 1);  // dst = edge_index[1][e]
}

__global__ void k_blocksum(const int* __restrict__ deg, int* bsum, int n) {
  __shared__ int s[256];
  int t = threadIdx.x;
  int i = blockIdx.x * 256 + t;
  s[t] = (i < n) ? (deg[i] - 1) : 0;
  __syncthreads();
  for (int o = 128; o > 0; o >>= 1) {
    if (t < o) s[t] += s[t + o];
    __syncthreads();
  }
  if (t == 0) bsum[blockIdx.x] = s[0];
}

__global__ void k_scanb(const int* __restrict__ bsum, int* bofs, int nb) {
  __shared__ int s[256];
  int t = threadIdx.x;
  int v = (t < nb) ? bsum[t] : 0;
  s[t] = v;
  __syncthreads();
  for (int o = 1; o < 256; o <<= 1) {
    int x = (t >= o) ? s[t - o] : 0;
    __syncthreads();
    s[t] += x;
    __syncthreads();
  }
  bofs[t] = s[t] - v;  // exclusive
}

__global__ void k_rowptr(const int* __restrict__ deg, const int* __restrict__ bofs,
                         int* rowptr, int* cursor, float* dinv, int n) {
  __shared__ int s[256];
  int t = threadIdx.x;
  int i = blockIdx.x * 256 + t;
  int d = (i < n) ? deg[i] : 1;
  int v = (i < n) ? (d - 1) : 0;
  s[t] = v;
  __syncthreads();
  for (int o = 1; o < 256; o <<= 1) {
    int x = (t >= o) ? s[t - o] : 0;
    __syncthreads();
    s[t] += x;
    __syncthreads();
  }
  int excl = s[t] - v + bofs[blockIdx.x];
  if (i < n) {
    rowptr[i] = excl;
    cursor[i] = excl;
    dinv[i] = rsqrtf((float)d);
    if (i == n - 1) rowptr[n] = excl + v;
  }
}

// pack (src, dinv[src]) per edge: no dependent scattered dinv load in agg
__global__ void k_fill(const int* __restrict__ ei, int* cursor,
                       const float* __restrict__ dinv, int2* colw, int E) {
  int e = blockIdx.x * 256 + threadIdx.x;
  if (e >= E) return;
  int s = ei[e];
  int d = ei[E + e];
  int pos = atomicAdd(&cursor[d], 1);
  colw[pos] = make_int2(s, __float_as_int(dinv[s]));
}

// transpose + bf16 convert weights: W[K][N] f32 -> Wt[N][K] bf16
__global__ void k_twt(const float* __restrict__ W, u16* __restrict__ Wt, int K, int N) {
  int i = blockIdx.x * 256 + threadIdx.x;
  if (i >= K * N) return;
  int k = i / N, n = i - k * N;
  Wt[n * K + k] = f2bf(W[i]);
}

// ---------------- GEMM: C[M,ldc](bf16) = A[M,K] @ Bt[*,K]^T ----------------
// BM x 128 tile, BK=32, 4 waves (2x2 of (BM/2)x64), bf16 LDS both operands.
// A fp32 path: reg-staged (load early / cvt_pk+ds_write late, T14 split).
// A bf16 path + B: global_load_lds with pre-swizzled source, swizzled ds_read.

template <bool AF32, int K, int BM>
__launch_bounds__(256, 4)
__global__ void gemm_kernel(const void* __restrict__ Ap, const u16* __restrict__ Bt,
                            u16* __restrict__ C, int M, int ldc) {
  constexpr int NT = K / 32;
  constexpr int AE = BM * 32;          // A elems (bf16) per buffer
  constexpr int WROWS = BM / 2;        // wave tile rows
  constexpr int FI = WROWS / 16;       // A fragments per wave
  constexpr int NJA = BM / 64;         // A gld16 issues (bf16 path)
  __shared__ u16 As_[2][AE];
  __shared__ u16 Bs_[2][4096];

  const int tid = threadIdx.x;
  const int lane = tid & 63;
  const int wid = tid >> 6;
  const int wr = wid >> 1, wc = wid & 1;
  const long brow = (long)blockIdx.x * BM;
  const long bcol = (long)blockIdx.y * 128;

  // B staging ptrs (pre-swizzled global, linear LDS dest)
  const u16* bgp[2];
  u16* blp[2];
#pragma unroll
  for (int j = 0; j < 2; ++j) {
    int idx = j * 256 + tid;
    int row = idx >> 2;
    int u = (idx & 3) ^ (row & 3);
    bgp[j] = Bt + (bcol + row) * (long)K + u * 8;
    blp[j] = &Bs_[0][idx * 8];
  }

  // A staging state
  const float* apf = nullptr;
  int arow = 0, au0 = 0, au1 = 0;
  const u16* agp[NJA];
  u16* alp[NJA];
  if constexpr (AF32) {
    arow = tid >> 1;               // BM=128: row staged by this thread
    int khalf = tid & 1;           // which 16-float half of the 32-k row
    long grow = brow + arow; if (grow > (long)M - 1) grow = M - 1;
    apf = (const float*)Ap + grow * (long)K + khalf * 16;
    int sw = arow & 3;
    au0 = (2 * khalf) ^ sw;
    au1 = (2 * khalf + 1) ^ sw;
  } else {
#pragma unroll
    for (int j = 0; j < NJA; ++j) {
      int idx = j * 256 + tid;
      int row = idx >> 2;
      int u = (idx & 3) ^ (row & 3);
      long grow = brow + row; if (grow > (long)M - 1) grow = M - 1;
      agp[j] = (const u16*)Ap + grow * (long)K + u * 8;
      alp[j] = &As_[0][idx * 8];
    }
  }

  float4 fa[4];
  auto loadA = [&](int kt) {  // AF32 only: issue 4x float4 loads (early)
    const float4* p = (const float4*)(apf + kt * 32);
#pragma unroll
    for (int i = 0; i < 4; ++i) fa[i] = p[i];
  };
  auto writeA = [&](int buf) {  // AF32 only: cvt + swizzled ds_write (late)
    union { u32 w[8]; uint4 v[2]; } pk;
    asm("v_cvt_pk_bf16_f32 %0, %1, %2" : "=v"(pk.w[0]) : "v"(fa[0].x), "v"(fa[0].y));
    asm("v_cvt_pk_bf16_f32 %0, %1, %2" : "=v"(pk.w[1]) : "v"(fa[0].z), "v"(fa[0].w));
    asm("v_cvt_pk_bf16_f32 %0, %1, %2" : "=v"(pk.w[2]) : "v"(fa[1].x), "v"(fa[1].y));
    asm("v_cvt_pk_bf16_f32 %0, %1, %2" : "=v"(pk.w[3]) : "v"(fa[1].z), "v"(fa[1].w));
    asm("v_cvt_pk_bf16_f32 %0, %1, %2" : "=v"(pk.w[4]) : "v"(fa[2].x), "v"(fa[2].y));
    asm("v_cvt_pk_bf16_f32 %0, %1, %2" : "=v"(pk.w[5]) : "v"(fa[2].z), "v"(fa[2].w));
    asm("v_cvt_pk_bf16_f32 %0, %1, %2" : "=v"(pk.w[6]) : "v"(fa[3].x), "v"(fa[3].y));
    asm("v_cvt_pk_bf16_f32 %0, %1, %2" : "=v"(pk.w[7]) : "v"(fa[3].z), "v"(fa[3].w));
    *(uint4*)&As_[buf][arow * 32 + au0 * 8] = pk.v[0];
    *(uint4*)&As_[buf][arow * 32 + au1 * 8] = pk.v[1];
  };
  auto stageB = [&](int kt, int buf) {
#pragma unroll
    for (int j = 0; j < 2; ++j) gld16(bgp[j] + kt * 32, blp[j] + buf * 4096);
  };
  auto stageAg = [&](int kt, int buf) {
#pragma unroll
    for (int j = 0; j < NJA; ++j) gld16(agp[j] + kt * 32, alp[j] + buf * AE);
  };

  f32x4 acc[FI][4];
#pragma unroll
  for (int i = 0; i < FI; i++)
#pragma unroll
    for (int j = 0; j < 4; j++) acc[i][j] = (f32x4){0.f, 0.f, 0.f, 0.f};

  // prologue: tile 0 into buf 0
  if constexpr (AF32) {
    loadA(0);
    stageB(0, 0);
    writeA(0);
  } else {
    stageAg(0, 0);
    stageB(0, 0);
  }
  __syncthreads();

  int cur = 0;
  for (int kt = 0; kt < NT; ++kt) {
    const bool more = (kt + 1 < NT);
    if constexpr (AF32) {
      if (more) { loadA(kt + 1); stageB(kt + 1, cur ^ 1); }
    } else {
      if (more) { stageAg(kt + 1, cur ^ 1); stageB(kt + 1, cur ^ 1); }
    }

    bf16x8 af[FI], bfq[4];
#pragma unroll
    for (int i = 0; i < FI; i++) {
      const int row = wr * WROWS + i * 16 + (lane & 15);
      const int u = (lane >> 4) ^ (row & 3);
      af[i] = *(const bf16x8*)&As_[cur][row * 32 + u * 8];
    }
#pragma unroll
    for (int j = 0; j < 4; j++) {
      const int row = wc * 64 + j * 16 + (lane & 15);
      const int u = (lane >> 4) ^ (row & 3);
      bfq[j] = *(const bf16x8*)&Bs_[cur][row * 32 + u * 8];
    }
#pragma unroll
    for (int i = 0; i < FI; i++)
#pragma unroll
      for (int j = 0; j < 4; j++)
        acc[i][j] = __builtin_amdgcn_mfma_f32_16x16x32_bf16(af[i], bfq[j], acc[i][j], 0, 0, 0);

    if constexpr (AF32) {
      if (more) writeA(cur ^ 1);  // vmcnt-wait on fa hidden behind the MFMAs above
    }
    __syncthreads();
    cur ^= 1;
  }

#pragma unroll
  for (int i = 0; i < FI; i++) {
    const long r0 = brow + wr * WROWS + i * 16 + ((lane >> 4) * 4);
#pragma unroll
    for (int j = 0; j < 4; j++) {
      const long cc = bcol + wc * 64 + j * 16 + (lane & 15);
#pragma unroll
      for (int q = 0; q < 4; q++) {
        long r = r0 + q;
        if (r < M) C[r * (long)ldc + cc] = f2bf(acc[i][j][q]);
      }
    }
  }
}

// ---------------- Aggregation (one wave per node, full-row gather) ----------------
// 64 lanes x 8B = full 512B (or 256B) row per load; 8 rows in flight for MLP.
// out[dst] = di*( sum_e w_e*h[src_e] ) + di^2*h[dst] + b  (+ReLU / sigmoid)

__device__ __forceinline__ float sigmoidf_(float x) { return 1.f / (1.f + __expf(-x)); }

__launch_bounds__(256)
__global__ void agg1(const u16* __restrict__ h0, const int* __restrict__ rowptr,
                     const int2* __restrict__ colw, const float* __restrict__ dinv,
                     const float* __restrict__ b1, u16* __restrict__ h, int n) {
  const int wid = threadIdx.x >> 6, lane = threadIdx.x & 63;
  const int node = blockIdx.x * 4 + wid;
  if (node >= n) return;
  const float di = dinv[node];
  ushort4 sv = ((const ushort4*)(h0 + (size_t)node * 256))[lane];
  float a0 = di * bf2f(sv.x), a1 = di * bf2f(sv.y), a2 = di * bf2f(sv.z), a3 = di * bf2f(sv.w);
  int e = rowptr[node];
  const int r1 = rowptr[node + 1];
  for (; e + 8 <= r1; e += 8) {
    int2 c[8];
#pragma unroll
    for (int q = 0; q < 8; ++q) c[q] = colw[e + q];
    ushort4 v[8];
#pragma unroll
    for (int q = 0; q < 8; ++q)
      v[q] = ((const ushort4*)(h0 + (size_t)c[q].x * 256))[lane];
#pragma unroll
    for (int q = 0; q < 8; ++q) {
      float wv = __int_as_float(c[q].y);
      a0 += wv * bf2f(v[q].x); a1 += wv * bf2f(v[q].y);
      a2 += wv * bf2f(v[q].z); a3 += wv * bf2f(v[q].w);
    }
  }
  for (; e < r1; ++e) {
    int2 c = colw[e];
    float wv = __int_as_float(c.y);
    ushort4 v = ((const ushort4*)(h0 + (size_t)c.x * 256))[lane];
    a0 += wv * bf2f(v.x); a1 += wv * bf2f(v.y); a2 += wv * bf2f(v.z); a3 += wv * bf2f(v.w);
  }
  float4 bb = ((const float4*)b1)[lane];
  a0 = a0 * di + bb.x; a1 = a1 * di + bb.y; a2 = a2 * di + bb.z; a3 = a3 * di + bb.w;
  a0 = fmaxf(a0, 0.f); a1 = fmaxf(a1, 0.f); a2 = fmaxf(a2, 0.f); a3 = fmaxf(a3, 0.f);
  ushort4 o; o.x = f2bf(a0); o.y = f2bf(a1); o.z = f2bf(a2); o.w = f2bf(a3);
  ((ushort4*)(h + (size_t)node * 256))[lane] = o;
}

__launch_bounds__(256)
__global__ void agg2(const u16* __restrict__ h2, const int* __restrict__ rowptr,
                     const int2* __restrict__ colw, const float* __restrict__ dinv,
                     const float* __restrict__ b2, float* __restrict__ out, int n) {
  const int wid = threadIdx.x >> 6, lane = threadIdx.x & 63;
  const int node = blockIdx.x * 4 + wid;
  if (node >= n) return;
  const float di = dinv[node];
  ushort2 sv = ((const ushort2*)(h2 + (size_t)node * 128))[lane];
  float a0 = di * bf2f(sv.x), a1 = di * bf2f(sv.y);
  int e = rowptr[node];
  const int r1 = rowptr[node + 1];
  for (; e + 8 <= r1; e += 8) {
    int2 c[8];
#pragma unroll
    for (int q = 0; q < 8; ++q) c[q] = colw[e + q];
    ushort2 v[8];
#pragma unroll
    for (int q = 0; q < 8; ++q)
      v[q] = ((const ushort2*)(h2 + (size_t)c[q].x * 128))[lane];
#pragma unroll
    for (int q = 0; q < 8; ++q) {
      float wv = __int_as_float(c[q].y);
      a0 += wv * bf2f(v[q].x); a1 += wv * bf2f(v[q].y);
    }
  }
  for (; e < r1; ++e) {
    int2 c = colw[e];
    float wv = __int_as_float(c.y);
    ushort2 v = ((const ushort2*)(h2 + (size_t)c.x * 128))[lane];
    a0 += wv * bf2f(v.x); a1 += wv * bf2f(v.y);
  }
  float2 bb = ((const float2*)b2)[lane];
  float2 o;
  o.x = sigmoidf_(a0 * di + bb.x);
  o.y = sigmoidf_(a1 * di + bb.y);
  ((float2*)(out + (size_t)node * 128))[lane] = o;
}

// ---------------- launch ----------------

extern "C" void kernel_launch(void* const* d_in, const int* in_sizes, int n_in,
                              void* d_out, int out_size, void* d_ws, size_t ws_size,
                              hipStream_t stream) {
  const float* x  = (const float*)d_in[0];
  const float* W1 = (const float*)d_in[1];
  const float* b1 = (const float*)d_in[2];
  const float* W2 = (const float*)d_in[3];
  const float* b2 = (const float*)d_in[4];
  const int*   ei = (const int*)d_in[5];

  const int N = in_sizes[0] / 512;
  const int E = in_sizes[5] / 2;
  const int Mpad = (N + 127) & ~127;
  float* outp = (float*)d_out;

  char* w = (char*)d_ws;
  size_t off = 0;
  auto take = [&](size_t bytes) -> void* {
    void* p = w + off;
    off = (off + bytes + 255) & ~(size_t)255;
    return p;
  };
  u16*   h0     = (u16*)take((size_t)Mpad * 256 * 2);
  u16*   hb     = (u16*)take((size_t)Mpad * 256 * 2);
  u16*   h2     = (u16*)take((size_t)Mpad * 128 * 2);
  u16*   W1t    = (u16*)take(256 * 512 * 2);
  u16*   W2t    = (u16*)take(128 * 256 * 2);
  int*   deg    = (int*)take((size_t)N * 4);
  float* dinv   = (float*)take((size_t)N * 4);
  int*   rowptr = (int*)take((size_t)(N + 1) * 4);
  int*   cursor = (int*)take((size_t)N * 4);
  int2*  colw   = (int2*)take((size_t)E * 8);
  int*   bsum   = (int*)take(256 * 4);
  int*   bofs   = (int*)take(256 * 4);
  (void)ws_size; (void)n_in; (void)out_size;

  const int nb = (N + 255) / 256;  // <=256 required by k_scanb
  const int eb = (E + 255) / 256;

  k_init_deg<<<nb, 256, 0, stream>>>(deg, N);
  k_count<<<eb, 256, 0, stream>>>(ei, deg, E);
  k_blocksum<<<nb, 256, 0, stream>>>(deg, bsum, N);
  k_scanb<<<1, 256, 0, stream>>>(bsum, bofs, nb);
  k_rowptr<<<nb, 256, 0, stream>>>(deg, bofs, rowptr, cursor, dinv, N);
  k_fill<<<eb, 256, 0, stream>>>(ei, cursor, dinv, colw, E);
  k_twt<<<(512 * 256 + 255) / 256, 256, 0, stream>>>(W1, W1t, 512, 256);
  k_twt<<<(256 * 128 + 255) / 256, 256, 0, stream>>>(W2, W2t, 256, 128);

  dim3 g1(Mpad / 128, 2);
  gemm_kernel<true, 512, 128><<<g1, 256, 0, stream>>>((const void*)x, W1t, h0, N, 256);
  agg1<<<(N + 3) / 4, 256, 0, stream>>>(h0, rowptr, colw, dinv, b1, hb, N);
  dim3 g2(Mpad / 64, 1);
  gemm_kernel<false, 256, 64><<<g2, 256, 0, stream>>>((const void*)hb, W2t, h2, Mpad, 128);
  agg2<<<(N + 3) / 4, 256, 0, stream>>>(h2, rowptr, colw, dinv, b2, outp, N);
}